// Round 11
// baseline (59.859 us; speedup 1.0000x reference)
//
#include <hip/hip_runtime.h>
#include <math.h>

#define BB 4
#define NN 6
#define DD 41
#define CC 64
#define FHh 16
#define FWw 44
#define NXg 200
#define NYg 200
#define NZg 1
#define NSLOT 128
#define NOVF  (FHh*DD)                 // 656 worst-case points per column
#define XYg (NXg*NYg)                  // 40000
#define NVOX (BB*NZg*NXg*NYg)          // 160000
#define NCOL (BB*NN*FWw)               // 1056 columns
#define NPIX (BB*NN*FHh*FWw)           // 16896
#define NCAM (BB*NN)                   // 24
#define NCH  (DD+CC)                   // 105

// ---- ws byte offsets ----
#define MAT_OFF 0u                      // 24 cams * 24 doubles = 4608 B
#define XFT_OFF 65536u                  // 24*44*105*16 floats = 7,096,320 B
#define WSV_OFF 8388608u                // 160000*64 floats = 40,960,000 B
#define WS_NEED (WSV_OFF + (unsigned)NVOX*CC*4u)   // ~49.3 MB

__device__ __forceinline__ void inv3x3d(const double m[9], double o[9]) {
    double a=m[0],b=m[1],c=m[2],d=m[3],e=m[4],f=m[5],g=m[6],h=m[7],i=m[8];
    double A = e*i - f*h;
    double Bv = -(d*i - f*g);
    double Cv = d*h - e*g;
    double det = a*A + b*Bv + c*Cv;
    double r = 1.0/det;
    o[0]=A*r;  o[1]=-(b*i-c*h)*r; o[2]=(b*f-c*e)*r;
    o[3]=Bv*r; o[4]=(a*i-c*g)*r;  o[5]=-(a*f-c*d)*r;
    o[6]=Cv*r; o[7]=-(a*h-b*g)*r; o[8]=(a*e-b*d)*r;
}

__global__ __launch_bounds__(256)
void lss_zero(float4* __restrict__ p, int n4)
{
    const int stride = gridDim.x * 256;
    for (int i = blockIdx.x * 256 + threadIdx.x; i < n4; i += stride)
        p[i] = make_float4(0.f, 0.f, 0.f, 0.f);
}

// K0: (a) blocks 0..167: transpose xf[cam][ch][h][w] -> xfT[cam][w][ch][h]
//     (b) block 168: per-camera f64 matrices -> mats[cam][24]
__global__ __launch_bounds__(256)
void lss_prep(const float* __restrict__ xf,
              const float* __restrict__ rots,
              const float* __restrict__ trans,
              const float* __restrict__ intr,
              const float* __restrict__ prots,
              const float* __restrict__ ptrans,
              double* __restrict__ mats,
              float* __restrict__ xfT)
{
    const int blk = blockIdx.x;
    const int tid = threadIdx.x;

    if (blk == NCAM * 7) {
        if (tid < NCAM) {
            const int cam = tid;
            double K9[9], P9[9], R9[9];
            #pragma unroll
            for (int i = 0; i < 9; ++i) {
                K9[i] = (double)intr [cam*9 + i];
                P9[i] = (double)prots[cam*9 + i];
                R9[i] = (double)rots [cam*9 + i];
            }
            double Kinv[9], Pinv[9];
            inv3x3d(K9, Kinv);
            inv3x3d(P9, Pinv);
            double* mp = mats + cam*24;
            #pragma unroll
            for (int i = 0; i < 9; ++i) mp[i] = Pinv[i];
            #pragma unroll
            for (int i = 0; i < 3; ++i)
                #pragma unroll
                for (int j = 0; j < 3; ++j)
                    mp[9 + i*3 + j] = R9[i*3+0]*Kinv[0*3+j] + R9[i*3+1]*Kinv[1*3+j]
                                    + R9[i*3+2]*Kinv[2*3+j];
            mp[18] = (double)trans [cam*3+0];
            mp[19] = (double)trans [cam*3+1];
            mp[20] = (double)trans [cam*3+2];
            mp[21] = (double)ptrans[cam*3+0];
            mp[22] = (double)ptrans[cam*3+1];
            mp[23] = (double)ptrans[cam*3+2];
        }
        return;
    }

    const int cam = blk / 7;
    const int chg = blk % 7;
    const int ch0 = chg * 16;
    const int cg  = (NCH - ch0 < 16) ? (NCH - ch0) : 16;   // 16 or 9

    __shared__ float tile[16*16*45];                       // [c][h][w pad45]
    // coalesced read: rows of 44 floats (176 B)
    for (int i = tid; i < cg*FHh*FWw; i += 256) {
        int c = i / (FHh*FWw);
        int r = i - c*(FHh*FWw);
        int h = r / FWw;
        int w = r - h*FWw;
        tile[(c*16 + h)*45 + w] =
            xf[(((size_t)cam*NCH + ch0 + c)*FHh + h)*FWw + w];
    }
    __syncthreads();
    // coalesced write: for each w, contiguous (c,h) run
    for (int i = tid; i < FWw*cg*FHh; i += 256) {
        int w = i / (cg*FHh);
        int r = i - w*(cg*FHh);
        int c = r / FHh;
        int h = r - c*FHh;
        xfT[((size_t)(cam*FWw + w)*NCH + ch0 + c)*FHh + h] =
            tile[(c*16 + h)*45 + w];
    }
}

// K2: one block per column; contiguous staging from xfT; hash dedup;
// one 64-lane contiguous atomic set per unique voxel into wsv[vox][64c].
__global__ __launch_bounds__(256)
void lss_scatter2(const float* __restrict__ xfT,
                  const double* __restrict__ mats,
                  float* __restrict__ wsv)
{
    __shared__ float s_lg[DD * 17];          // [d][h] pad 17
    __shared__ float s_feat[CC * 17];        // [c][h] pad 17
    __shared__ float s_coef[NSLOT * 17];     // [slot][h] pad 17
    __shared__ int   s_keys[NSLOT];
    __shared__ short s_list[NSLOT];
    __shared__ int   s_nslot;
    __shared__ int2  s_ovf[NOVF];
    __shared__ float s_ovfw[NOVF];
    __shared__ int   s_ovfcnt;

    const int tid  = threadIdx.x;
    const int lane = tid & 63;
    const int wv   = tid >> 6;          // 0..3

    // XCD swizzle: 1056 = 8*132
    const int obid = blockIdx.x;
    const int bid  = (obid & 7) * (NCOL / 8) + (obid >> 3);
    const int w   = bid % FWw;
    const int rem = bid / FWw;
    const int n   = rem % NN;
    const int b   = rem / NN;
    const int cam = b*NN + n;

    if (tid < NSLOT) s_keys[tid] = -1;
    for (int i = tid; i < NSLOT*17; i += 256) s_coef[i] = 0.0f;
    if (tid == 0) { s_nslot = 0; s_ovfcnt = 0; }

    // ---- contiguous staging: column = 1680 consecutive floats ----
    {
        const float4* col4 = (const float4*)(xfT + (size_t)(cam*FWw + w) * (NCH*FHh));
        for (int t4 = tid; t4 < (NCH*FHh)/4; t4 += 256) {   // 420 float4
            float4 v = col4[t4];
            int t  = t4 << 2;
            int ch = t >> 4;
            int h0 = t & 15;                                // 0,4,8,12
            float* dst = (ch < DD) ? &s_lg[ch*17 + h0]
                                   : &s_feat[(ch - DD)*17 + h0];
            dst[0] = v.x; dst[1] = v.y; dst[2] = v.z; dst[3] = v.w;
        }
    }

    // ---- per-camera matrices (precomputed, block-uniform) ----
    const double* mp = mats + cam*24;
    double Pi[9], Mm[9];
    #pragma unroll
    for (int i = 0; i < 9; ++i) { Pi[i] = mp[i]; Mm[i] = mp[9+i]; }
    const double tx  = mp[18], ty  = mp[19], tz  = mp[20];
    const double ptx = mp[21], pty = mp[22], ptz = mp[23];

    __syncthreads();

    // ---- softmax + geometry + hash insert; wave wv: h = 4wv..4wv+3 ----
    int      last_vox  = -1;
    unsigned last_slot = 0;
    for (int r = 0; r < 4; ++r) {
        const int h = (wv << 2) + r;
        float logit = (lane < DD) ? s_lg[lane*17 + h] : -INFINITY;
        float mx = logit;
        #pragma unroll
        for (int off = 32; off; off >>= 1) mx = fmaxf(mx, __shfl_xor(mx, off));
        float ex = (lane < DD) ? expf(logit - mx) : 0.0f;
        float sm = ex;
        #pragma unroll
        for (int off = 32; off; off >>= 1) sm += __shfl_xor(sm, off);
        const float wgt = ex / sm;

        int vox = -1;
        if (lane < DD) {
            double dz = 4.0 + (double)lane;
            double xs = (double)w * (703.0/43.0);
            double ys = (double)h * 17.0;
            double px = xs - ptx, py = ys - pty, pz = dz - ptz;
            double qx = Pi[0]*px + Pi[1]*py + Pi[2]*pz;
            double qy = Pi[3]*px + Pi[4]*py + Pi[5]*pz;
            double qz = Pi[6]*px + Pi[7]*py + Pi[8]*pz;
            qx *= qz; qy *= qz;
            double gx = Mm[0]*qx + Mm[1]*qy + Mm[2]*qz + tx;
            double gy = Mm[3]*qx + Mm[4]*qy + Mm[5]*qz + ty;
            double gz = Mm[6]*qx + Mm[7]*qy + Mm[8]*qz + tz;
            double fx = floor((gx + 50.0) / 0.5);
            double fy = floor((gy + 50.0) / 0.5);
            double fz = floor((gz + 10.0) / 20.0);
            if (fx >= 0.0 && fx < (double)NXg &&
                fy >= 0.0 && fy < (double)NYg &&
                fz >= 0.0 && fz < (double)NZg) {
                int ix = (int)fx, iy = (int)fy, iz = (int)fz;
                vox = ((b*NZg + iz)*NXg + ix)*NYg + iy;
            }
        }

        if (vox >= 0) {
            if (vox == last_vox) {
                atomicAdd(&s_coef[last_slot*17 + h], wgt);
            } else {
                unsigned slot = (((unsigned)vox * 2654435761u) >> 18) & (NSLOT-1);
                bool done = false;
                for (int probe = 0; probe < NSLOT; ++probe) {
                    int prev = atomicCAS(&s_keys[slot], -1, vox);
                    if (prev == -1) {
                        int k = atomicAdd(&s_nslot, 1);
                        s_list[k] = (short)slot;
                    }
                    if (prev == -1 || prev == vox) {
                        atomicAdd(&s_coef[slot*17 + h], wgt);
                        last_vox = vox; last_slot = slot;
                        done = true;
                        break;
                    }
                    slot = (slot + 1) & (NSLOT-1);
                }
                if (!done) {
                    int k = atomicAdd(&s_ovfcnt, 1);
                    s_ovf[k]  = make_int2(vox, h);
                    s_ovfw[k] = wgt;
                    last_vox = -1;
                }
            }
        }
    }

    __syncthreads();

    // ---- emit: one 64-lane contiguous atomic set per unique voxel ----
    const int nocc = s_nslot;
    for (int e = wv; e < nocc; e += 4) {
        int slot = s_list[e];
        int vox  = s_keys[slot];
        float acc = 0.0f;
        #pragma unroll
        for (int h = 0; h < FHh; ++h)
            acc += s_coef[slot*17 + h] * s_feat[lane*17 + h];
        atomicAdd(&wsv[(size_t)vox * CC + lane], acc);
    }
    // ---- overflow entries (rare, generic fallback) ----
    const int novf = s_ovfcnt;
    for (int e = wv; e < novf; e += 4) {
        int vox = s_ovf[e].x, h = s_ovf[e].y;
        atomicAdd(&wsv[(size_t)vox * CC + lane], s_ovfw[e] * s_feat[lane*17 + h]);
    }
}

// K3: ws [bz][40000 xy][64 c] -> out [bz][64 c][40000 xy]
__global__ __launch_bounds__(256)
void lss_transpose_c(const float* __restrict__ ws, float* __restrict__ out)
{
    __shared__ float tile[CC][65];
    const int blk  = blockIdx.x;            // 4*625
    const int bz   = blk / 625;
    const int xy0  = (blk % 625) * 64;
    const int t    = threadIdx.x;
    const int lane = t & 63;
    const int wv   = t >> 6;

    const float4* src = (const float4*)(ws + ((size_t)bz * XYg + xy0) * CC);
    #pragma unroll
    for (int rep = 0; rep < 4; ++rep) {
        int idx = (wv << 8) + (rep << 6) + lane;   // 64 consecutive float4/wave
        int xyl = idx >> 4;
        int c4  = idx & 15;
        float4 v = src[idx];
        tile[(c4<<2)+0][xyl] = v.x;
        tile[(c4<<2)+1][xyl] = v.y;
        tile[(c4<<2)+2][xyl] = v.z;
        tile[(c4<<2)+3][xyl] = v.w;
    }
    __syncthreads();
    float* dst = out + (size_t)bz * CC * XYg + xy0;
    #pragma unroll
    for (int rep = 0; rep < 4; ++rep) {
        int c = (wv << 4) + (rep << 2) + (lane >> 4);
        int q = lane & 15;
        float4 v = make_float4(tile[c][(q<<2)+0], tile[c][(q<<2)+1],
                               tile[c][(q<<2)+2], tile[c][(q<<2)+3]);
        ((float4*)(dst + (size_t)c * XYg))[q] = v;
    }
}

// ---------------- fallback (tiny ws): zero out + direct atomics -------------
__global__ __launch_bounds__(256)
void lss_scatter_direct(const float* __restrict__ xf,
                        const float* __restrict__ rots,
                        const float* __restrict__ trans,
                        const float* __restrict__ intr,
                        const float* __restrict__ prots,
                        const float* __restrict__ ptrans,
                        float* __restrict__ acc)
{
    const int wid  = blockIdx.x * 4 + (threadIdx.x >> 6);
    const int lane = threadIdx.x & 63;
    if (wid >= NPIX) return;
    int w  = wid % FWw;
    int t1 = wid / FWw;
    int h  = t1 % FHh; t1 /= FHh;
    int n  = t1 % NN;
    int b  = t1 / NN;
    const int cam = b*NN + n;

    double K9[9], P9[9], R9[9];
    #pragma unroll
    for (int i = 0; i < 9; ++i) {
        K9[i] = (double)intr [cam*9 + i];
        P9[i] = (double)prots[cam*9 + i];
        R9[i] = (double)rots [cam*9 + i];
    }
    double Kinv[9], Pinv[9];
    inv3x3d(K9, Kinv);
    inv3x3d(P9, Pinv);
    double M[9];
    #pragma unroll
    for (int i = 0; i < 3; ++i)
        #pragma unroll
        for (int j = 0; j < 3; ++j)
            M[i*3+j] = R9[i*3+0]*Kinv[0*3+j] + R9[i*3+1]*Kinv[1*3+j] + R9[i*3+2]*Kinv[2*3+j];
    const double tx  = (double)trans [cam*3+0], ty  = (double)trans [cam*3+1], tz  = (double)trans [cam*3+2];
    const double ptx = (double)ptrans[cam*3+0], pty = (double)ptrans[cam*3+1], ptz = (double)ptrans[cam*3+2];

    const size_t pixoff = (size_t)cam * NCH * FHh * FWw + (size_t)h * FWw + w;
    float logit = (lane < DD) ? xf[pixoff + (size_t)lane * (FHh*FWw)] : -INFINITY;
    float mx = logit;
    #pragma unroll
    for (int off = 32; off; off >>= 1) mx = fmaxf(mx, __shfl_xor(mx, off));
    float ex = (lane < DD) ? expf(logit - mx) : 0.0f;
    float sm = ex;
    #pragma unroll
    for (int off = 32; off; off >>= 1) sm += __shfl_xor(sm, off);
    const float wgt = ex / sm;

    int baddr = -1;
    if (lane < DD) {
        double dz = 4.0 + (double)lane;
        double xs = (double)w * (703.0/43.0);
        double ys = (double)h * 17.0;
        double px = xs - ptx, py = ys - pty, pz = dz - ptz;
        double qx = Pinv[0]*px + Pinv[1]*py + Pinv[2]*pz;
        double qy = Pinv[3]*px + Pinv[4]*py + Pinv[5]*pz;
        double qz = Pinv[6]*px + Pinv[7]*py + Pinv[8]*pz;
        qx *= qz; qy *= qz;
        double gx = M[0]*qx + M[1]*qy + M[2]*qz + tx;
        double gy = M[3]*qx + M[4]*qy + M[5]*qz + ty;
        double gz = M[6]*qx + M[7]*qy + M[8]*qz + tz;
        double fx = floor((gx + 50.0) / 0.5);
        double fy = floor((gy + 50.0) / 0.5);
        double fz = floor((gz + 10.0) / 20.0);
        if (fx >= 0.0 && fx < (double)NXg &&
            fy >= 0.0 && fy < (double)NYg &&
            fz >= 0.0 && fz < (double)NZg) {
            int ix = (int)fx, iy = (int)fy, iz = (int)fz;
            int bz = b*NZg + iz;
            baddr = bz * (CC*XYg) + ix*NYg + iy;
        }
    }

    const float f = xf[pixoff + (size_t)(DD + lane) * (FHh*FWw)];
    for (int d = 0; d < DD; ++d) {
        int   a  = __shfl(baddr, d);
        float wd = __shfl(wgt,   d);
        if (a >= 0) atomicAdd(&acc[(size_t)a + (size_t)lane * XYg], wd * f);
    }
}

extern "C" void kernel_launch(void* const* d_in, const int* in_sizes, int n_in,
                              void* d_out, int out_size, void* d_ws, size_t ws_size,
                              hipStream_t stream) {
    const float* xf     = (const float*)d_in[0];
    const float* rots   = (const float*)d_in[1];
    const float* trans  = (const float*)d_in[2];
    const float* intr   = (const float*)d_in[3];
    const float* prots  = (const float*)d_in[4];
    const float* ptrans = (const float*)d_in[5];
    float* out = (float*)d_out;

    if (ws_size >= (size_t)WS_NEED) {
        char* wsb = (char*)d_ws;
        double* mats = (double*)(wsb + MAT_OFF);
        float*  xfT  = (float*) (wsb + XFT_OFF);
        float*  wsv  = (float*) (wsb + WSV_OFF);
        lss_prep<<<dim3(NCAM*7 + 1), dim3(256), 0, stream>>>(
            xf, rots, trans, intr, prots, ptrans, mats, xfT);
        lss_zero<<<dim3(2048), dim3(256), 0, stream>>>(
            (float4*)wsv, (NVOX*CC)/4);
        lss_scatter2<<<dim3(NCOL), dim3(256), 0, stream>>>(xfT, mats, wsv);
        lss_transpose_c<<<dim3(BB*NZg*625), dim3(256), 0, stream>>>(wsv, out);
    } else {
        lss_zero<<<dim3(2048), dim3(256), 0, stream>>>(
            (float4*)out, (BB*NZg*XYg*CC)/4);
        lss_scatter_direct<<<dim3((NPIX + 3) / 4), dim3(256), 0, stream>>>(
            xf, rots, trans, intr, prots, ptrans, out);
    }
}